// Round 17
// baseline (90.341 us; speedup 1.0000x reference)
//
#include <hip/hip_runtime.h>
#include <hip/hip_bf16.h>
#include <hip/hip_cooperative_groups.h>
#include <math.h>

namespace cg = cooperative_groups;

typedef __bf16 bf16x4 __attribute__((ext_vector_type(4)));
typedef __bf16 bf16x8 __attribute__((ext_vector_type(8)));
typedef float  f32x4  __attribute__((ext_vector_type(4)));

#define HW 16384   // 128*128
#define CCH 64
#define OCH 64

__device__ static const float FIRTAB[62] = {
  // db4 (8)
  -0.0105974017850021f, 0.0328830116668852f, 0.0308413818355607f, -0.1870348117188811f,
  -0.0279837694169839f, 0.6308807679295904f, 0.7148465705529155f, 0.2303778133088964f,
  // db6 (12)
  0.00107730108499558f, -0.00477725751101065f, -0.0005538422009938f, 0.03158203931748603f,
  0.02752286553030533f, -0.0975016055873225f, -0.12976686756709563f, 0.22626469396544f,
  0.3152503517092432f, -0.7511339080210959f, 0.4946238903984534f, 0.1115407433501095f,
  // sym6 (12)
  -0.007800708325034148f, 0.001767711864242804f, 0.04472490177066578f, -0.02106029251230056f,
  -0.0726375227866f, 0.3379294217282401f, 0.787641141030194f, 0.4910559419267466f,
  -0.048311742585632f, -0.1179901111484105f, 0.00349071208421747f, 0.01540410932702737f,
  // coif5 (30)
  -3.459977283621256e-05f, -7.098330313814114e-05f, 0.0004662169601128863f, 0.001117518770890601f,
  -0.002574517688750223f, -0.00900797613666158f, 0.015880544863615904f, 0.03455502757306163f,
  -0.08230192710688598f, -0.07179982161931202f, 0.42848347637761874f, 0.7937772226256206f,
  0.4051769024096169f, -0.06112339000267287f, -0.06577191128185562f, 0.023452696141836267f,
  0.007782596427325418f, -0.003793512864491014f, -0.0002606761356811993f, 0.000107502882505652f,
  1.10319778524429e-05f, -5.520763127949e-06f, -1.0682196848076e-06f, 5.236425333584e-07f,
  1.125098976034e-07f, -5.417490769329e-08f, -8.8631e-09f, 4.2921e-09f, 6.7e-10f, -3.2e-10f
};
__device__ static const int FIR_OFF[4] = {0, 8, 20, 32};
__device__ static const int FIR_LEN[4] = {8, 12, 12, 30};

struct PS {   // P-build scratch (~64 KB)
  float tmpA[62][64];
  float tmpD[62][64];
  float matA[64][64];
  float matD[64][64];
  float pwrow[128];
  float rawS[32], loS[32], hiS[32];
};
struct MS {   // main-tile storage (40 KB)
  unsigned char xt[256 * 128];
  float wmld[256 * 8];
};
union SU { PS p; MS m; };

// ---------------------------------------------------------------------------
// P-build SLICE: wavelet k, output row o. Redundant T-build + resize (cheap,
// fully parallel), fold of ONE row. 384 slices = 6 k x 64 o.
// Proven math/layout from R14: entry (k,o,c) -> Pout[(((s*4+mf)*64+lane)<<3)+e]
//   s = 2k+(c>>5), mf = o>>4, lane = (o&15)|(((c&31)>>3)<<4), e = c&7
// ---------------------------------------------------------------------------
__device__ __forceinline__ void build_P_slice(
    PS& S, int k, int o, int t,
    const float* __restrict__ pw,
    const float* __restrict__ s53A, const float* __restrict__ s53D,
    const float* __restrict__ s97A, const float* __restrict__ s97D,
    __bf16* __restrict__ Pout)
{
  if (t < 128) S.pwrow[t] = pw[o * 128 + t];

  if (k < 4) {
    const int L = FIR_LEN[k], off = FIR_OFF[k];
    const int pl = (L - 1) / 2 - 1;          // even L for all four FIRs

    if (t < L) S.rawS[t] = FIRTAB[off + t];
    __syncthreads();
    float ss = 0.f;
    for (int l = 0; l < L; ++l) { float vv = S.rawS[l]; ss += vv * vv; }
    const float inv = 1.f / (sqrtf(ss) + 1e-12f);
    if (t < L) {
      S.loS[t] = S.rawS[t] * inv;
      S.hiS[t] = ((t & 1) ? -1.f : 1.f) * S.rawS[L - 1 - t] * inv;
    }
    __syncthreads();

    for (int e = t; e < 62 * 64; e += 256) {
      const int i = e >> 6, c = e & 63;
      const int base = pl - i;
      const int l1 = c + base;
      const int l2 = -c + base;
      const int l3 = 126 - c + base;
      float va = 0.f, vd = 0.f;
      if (l1 >= 0 && l1 < L)           { va += S.loS[l1]; vd += S.hiS[l1]; }
      if (c > 0 && l2 >= 0 && l2 < L)  { va += S.loS[l2]; vd += S.hiS[l2]; }
      if (c < 63 && l3 >= 0 && l3 < L) { va += S.loS[l3]; vd += S.hiS[l3]; }
      S.tmpA[i][c] = va; S.tmpD[i][c] = vd;
    }
    __syncthreads();
  } else {
    for (int e = t; e < 32 * 64; e += 256) {
      const int i = e >> 6, c = e & 63;
      S.tmpA[i][c] = (c == 2 * i)     ? 1.f : 0.f;
      S.tmpD[i][c] = (c == 2 * i + 1) ? 1.f : 0.f;
    }
    float cf[4]; int nst;
    if (k == 4) { cf[0] = -0.5f; cf[1] = 0.25f; cf[2] = 0.f; cf[3] = 0.f; nst = 2; }
    else { cf[0] = -1.586134342f; cf[1] = -0.05298011854f;
           cf[2] = 0.8829110762f; cf[3] = 0.4435068522f; nst = 4; }
    __syncthreads();
    for (int s = 0; s < nst; ++s) {
      for (int e = t; e < 32 * 64; e += 256) {
        const int i = e >> 6, c = e & 63;
        const int im = (i == 0) ? 1 : i - 1;
        const int ip = (i == 31) ? 30 : i + 1;
        if ((s & 1) == 0)
          S.tmpD[i][c] += cf[s] * 0.5f * (S.tmpA[im][c] + S.tmpA[ip][c]);
        else
          S.tmpA[i][c] += cf[s] * 0.5f * (S.tmpD[im][c] + S.tmpD[ip][c]);
      }
      __syncthreads();
    }
  }

  {
    const int Lin = (k < 4) ? 62 : 32;
    float sA = 1.f, sD = 1.f;
    if (k == 4) { sA = s53A[0]; sD = s53D[0]; }
    if (k == 5) { sA = s97A[0]; sD = s97D[0]; }
    const float step = (float)Lin / 64.0f;
    for (int e = t; e < 64 * 64; e += 256) {
      const int oo = e >> 6, c = e & 63;
      float src = (oo + 0.5f) * step - 0.5f;
      src = fmaxf(src, 0.f);
      int i0 = (int)floorf(src); if (i0 > Lin - 1) i0 = Lin - 1;
      int i1 = i0 + 1;           if (i1 > Lin - 1) i1 = Lin - 1;
      float w = src - (float)i0;
      S.matA[oo][c] = sA * ((1.f - w) * S.tmpA[i0][c] + w * S.tmpA[i1][c]);
      S.matD[oo][c] = sD * ((1.f - w) * S.tmpD[i0][c] + w * S.tmpD[i1][c]);
    }
  }
  __syncthreads();

  if (t < 64) {
    const int c = t;
    float acc = 0.f;
    #pragma unroll 8
    for (int j = 0; j < 64; ++j)
      acc += S.pwrow[j] * S.matA[j][c] + S.pwrow[64 + j] * S.matD[j][c];
    const int s = k * 2 + (c >> 5);
    const int mf = o >> 4;
    const int lane = (o & 15) | (((c & 31) >> 3) << 4);
    const int e = c & 7;
    Pout[(((s * 4 + mf) * 64 + lane) << 3) + e] = (__bf16)acc;
  }
  __syncthreads();   // scratch free before xt reuse
}

// ---------------------------------------------------------------------------
// FUSED cooperative kernel v2: 512 blocks x 256 threads, 2 blocks/CU.
//  Blocks 0..383: build ONE P-slice FIRST (no staging regs live -> no spill),
//  then join the normal path. All blocks: stage x, write xt, gate own pgs,
//  grid.sync (P visible + block barrier), A-frags from L2-hot Pws, phase B.
// ---------------------------------------------------------------------------
__global__ __launch_bounds__(256, 2) void fused(
    const float* __restrict__ xg,
    const float* __restrict__ gw1, const float* __restrict__ gb1,
    const float* __restrict__ gw2, const float* __restrict__ gb2,
    const float* __restrict__ pw,  const float* __restrict__ pbias,
    const float* __restrict__ s53A, const float* __restrict__ s53D,
    const float* __restrict__ s97A, const float* __restrict__ s97D,
    __bf16* __restrict__ Pws,
    float* __restrict__ outg)
{
  __shared__ __align__(16) SU u;

  const int t    = threadIdx.x;
  const int w    = t >> 6;
  const int lane = t & 63;
  const int lr   = lane & 15;
  const int kq   = lane >> 4;

  const int blk   = blockIdx.x;
  const int b     = blk >> 6;                 // 64 tiles per image
  const int pbase = (blk & 63) << 8;          // 256 px per tile

  // ---- P-build FIRST on blocks 0..383 (uniform ~1-2us delay, no spill) ----
  if (blk < 384)
    build_P_slice(u.p, blk >> 6, blk & 63, t, pw, s53A, s53D, s97A, s97D, Pws);

  // ---- staging: wave w owns px [w*64, w*64+64), thread = (quad, 16ch) ----
  const int pq  = lane & 15;
  const int cg  = lane >> 4;
  const int px0 = w * 64 + pq * 4;

  const float* s = xg + (size_t)b * (CCH * HW) + (size_t)(cg * 16) * HW + pbase + px0;
  f32x4 v[16];
  #pragma unroll
  for (int r = 0; r < 16; ++r) v[r] = *(const f32x4*)(s + (size_t)r * HW);

  // ---- per-wave gate constants ----
  bf16x8 W1a[2];
  {
    const float* wp = gw1 + lr * 64 + kq * 8;
    #pragma unroll
    for (int hh = 0; hh < 2; ++hh) {
      f32x4 lo = *(const f32x4*)(wp + hh * 32);
      f32x4 hi = *(const f32x4*)(wp + hh * 32 + 4);
      bf16x8 a;
      #pragma unroll
      for (int e = 0; e < 4; ++e) { a[e] = (__bf16)lo[e]; a[e + 4] = (__bf16)hi[e]; }
      W1a[hh] = a;
    }
  }
  const f32x4 gb1v  = *(const f32x4*)(gb1 + kq * 4);
  const f32x4 biasv = *(const f32x4*)(pbias + w * 16 + kq * 4);

  // ---- write own 16ch x 4px into swizzled bf16 tile ----
  #pragma unroll
  for (int i = 0; i < 4; ++i) {
    const int px = px0 + i;
    bf16x8 w0, w1;
    #pragma unroll
    for (int e = 0; e < 8; ++e) { w0[e] = (__bf16)v[e][i]; w1[e] = (__bf16)v[8 + e][i]; }
    *(bf16x8*)&u.m.xt[px * 128 + (((cg * 2)     ^ (px & 7)) << 4)] = w0;
    *(bf16x8*)&u.m.xt[px * 128 + (((cg * 2 + 1) ^ (px & 7)) << 4)] = w1;
  }

  // ---- phase A: gate the wave's OWN four pixel-groups (pre-sync) ----
  #pragma unroll
  for (int pp = 0; pp < 4; ++pp) {
    const int col = (w * 4 + pp) * 16 + lr;
    const bf16x8 B0 = *(const bf16x8*)&u.m.xt[col * 128 + ((kq       ^ (col & 7)) << 4)];
    const bf16x8 B1 = *(const bf16x8*)&u.m.xt[col * 128 + (((4 + kq) ^ (col & 7)) << 4)];

    f32x4 h = {0.f, 0.f, 0.f, 0.f};
    h = __builtin_amdgcn_mfma_f32_16x16x32_bf16(W1a[0], B0, h, 0, 0, 0);
    h = __builtin_amdgcn_mfma_f32_16x16x32_bf16(W1a[1], B1, h, 0, 0, 0);
    float hr[4];
    #pragma unroll
    for (int j = 0; j < 4; ++j) hr[j] = fmaxf(h[j] + gb1v[j], 0.f);

    float lg[6];
    #pragma unroll
    for (int kk = 0; kk < 6; ++kk) {
      const f32x4 w2 = *(const f32x4*)(gw2 + kk * 16 + kq * 4);
      lg[kk] = w2[0] * hr[0] + w2[1] * hr[1] + w2[2] * hr[2] + w2[3] * hr[3];
    }
    #pragma unroll
    for (int kk = 0; kk < 6; ++kk) lg[kk] += __shfl_xor(lg[kk], 16);
    #pragma unroll
    for (int kk = 0; kk < 6; ++kk) lg[kk] += __shfl_xor(lg[kk], 32);
    #pragma unroll
    for (int kk = 0; kk < 6; ++kk) lg[kk] += gb2[kk];

    float mx = fmaxf(fmaxf(fmaxf(lg[0], lg[1]), fmaxf(lg[2], lg[3])), fmaxf(lg[4], lg[5]));
    float ex[6], ssum = 0.f;
    #pragma unroll
    for (int kk = 0; kk < 6; ++kk) { ex[kk] = __expf(lg[kk] - mx); ssum += ex[kk]; }
    const float sinv = __builtin_amdgcn_rcpf(ssum);
    if (kq == 0) {
      f32x4 o0 = { ex[0] * sinv, ex[1] * sinv, ex[2] * sinv, ex[3] * sinv };
      f32x4 o1 = { ex[4] * sinv, ex[5] * sinv, 0.f, 0.f };
      *(f32x4*)&u.m.wmld[col * 8 + 0] = o0;
      *(f32x4*)&u.m.wmld[col * 8 + 4] = o1;
    }
  }

  // ---- grid-wide sync: Pws visible; also block-syncs xt/wmld ----
  cg::this_grid().sync();

  // ---- A-fragments from L2-hot Pws ----
  bf16x8 A[12];
  #pragma unroll
  for (int kk = 0; kk < 6; ++kk)
    #pragma unroll
    for (int sh = 0; sh < 2; ++sh)
      A[kk * 2 + sh] = *(const bf16x8*)(Pws + (size_t)((((2 * kk + sh) * 4 + w) * 64 + lane) << 3));

  // ---- phase B: main MFMA over all 16 pixel-groups, NT stores ----
  float* outb = outg + (size_t)b * (OCH * HW) + pbase;

  #pragma unroll
  for (int pg = 0; pg < 16; ++pg) {
    const int col = pg * 16 + lr;
    const bf16x8 B0 = *(const bf16x8*)&u.m.xt[col * 128 + ((kq       ^ (col & 7)) << 4)];
    const bf16x8 B1 = *(const bf16x8*)&u.m.xt[col * 128 + (((4 + kq) ^ (col & 7)) << 4)];
    const f32x4 wv0 = *(const f32x4*)&u.m.wmld[col * 8 + 0];
    const f32x4 wv1 = *(const f32x4*)&u.m.wmld[col * 8 + 4];
    const float wmv[6] = { wv0[0], wv0[1], wv0[2], wv0[3], wv1[0], wv1[1] };

    f32x4 facc = biasv;
    #pragma unroll
    for (int kk = 0; kk < 6; ++kk) {
      f32x4 y = {0.f, 0.f, 0.f, 0.f};
      y = __builtin_amdgcn_mfma_f32_16x16x32_bf16(A[2 * kk    ], B0, y, 0, 0, 0);
      y = __builtin_amdgcn_mfma_f32_16x16x32_bf16(A[2 * kk + 1], B1, y, 0, 0, 0);
      #pragma unroll
      for (int j = 0; j < 4; ++j) facc[j] += wmv[kk] * y[j];
    }
    #pragma unroll
    for (int j = 0; j < 4; ++j) {
      const int o = w * 16 + kq * 4 + j;
      __builtin_nontemporal_store(facc[j], &outb[(size_t)o * HW + col]);
    }
  }
}

// ---------------------------------------------------------------------------
// FALLBACK path (proven two-kernel form) used only if cooperative launch is
// unavailable. Identical outputs.
// ---------------------------------------------------------------------------
__global__ __launch_bounds__(256) void setup_P(
    const float* __restrict__ pw,
    const float* __restrict__ s53A, const float* __restrict__ s53D,
    const float* __restrict__ s97A, const float* __restrict__ s97D,
    __bf16* __restrict__ Pout)
{
  __shared__ __align__(16) PS S;
  build_P_slice(S, blockIdx.x >> 6, blockIdx.x & 63, threadIdx.x,
                pw, s53A, s53D, s97A, s97D, Pout);
}

__global__ __launch_bounds__(256, 2) void wavelet_main(
    const float* __restrict__ xg,
    const float* __restrict__ gw1, const float* __restrict__ gb1,
    const float* __restrict__ gw2, const float* __restrict__ gb2,
    const float* __restrict__ pbias,
    const __bf16* __restrict__ Pws,
    float* __restrict__ outg)
{
  __shared__ __align__(16) MS m;

  const int t    = threadIdx.x;
  const int w    = t >> 6;
  const int lane = t & 63;
  const int lr   = lane & 15;
  const int kq   = lane >> 4;

  const int blk   = blockIdx.x;
  const int b     = blk >> 6;
  const int pbase = (blk & 63) << 8;

  const int pq  = lane & 15;
  const int cg  = lane >> 4;
  const int px0 = w * 64 + pq * 4;

  const float* s = xg + (size_t)b * (CCH * HW) + (size_t)(cg * 16) * HW + pbase + px0;
  f32x4 v[16];
  #pragma unroll
  for (int r = 0; r < 16; ++r) v[r] = *(const f32x4*)(s + (size_t)r * HW);

  bf16x8 A[12];
  #pragma unroll
  for (int kk = 0; kk < 6; ++kk)
    #pragma unroll
    for (int sh = 0; sh < 2; ++sh)
      A[kk * 2 + sh] = *(const bf16x8*)(Pws + (size_t)((((2 * kk + sh) * 4 + w) * 64 + lane) << 3));

  bf16x8 W1a[2];
  {
    const float* wp = gw1 + lr * 64 + kq * 8;
    #pragma unroll
    for (int hh = 0; hh < 2; ++hh) {
      f32x4 lo = *(const f32x4*)(wp + hh * 32);
      f32x4 hi = *(const f32x4*)(wp + hh * 32 + 4);
      bf16x8 a;
      #pragma unroll
      for (int e = 0; e < 4; ++e) { a[e] = (__bf16)lo[e]; a[e + 4] = (__bf16)hi[e]; }
      W1a[hh] = a;
    }
  }
  const f32x4 gb1v  = *(const f32x4*)(gb1 + kq * 4);
  const f32x4 biasv = *(const f32x4*)(pbias + w * 16 + kq * 4);

  #pragma unroll
  for (int i = 0; i < 4; ++i) {
    const int px = px0 + i;
    bf16x8 w0, w1;
    #pragma unroll
    for (int e = 0; e < 8; ++e) { w0[e] = (__bf16)v[e][i]; w1[e] = (__bf16)v[8 + e][i]; }
    *(bf16x8*)&m.xt[px * 128 + (((cg * 2)     ^ (px & 7)) << 4)] = w0;
    *(bf16x8*)&m.xt[px * 128 + (((cg * 2 + 1) ^ (px & 7)) << 4)] = w1;
  }

  #pragma unroll
  for (int pp = 0; pp < 4; ++pp) {
    const int col = (w * 4 + pp) * 16 + lr;
    const bf16x8 B0 = *(const bf16x8*)&m.xt[col * 128 + ((kq       ^ (col & 7)) << 4)];
    const bf16x8 B1 = *(const bf16x8*)&m.xt[col * 128 + (((4 + kq) ^ (col & 7)) << 4)];

    f32x4 h = {0.f, 0.f, 0.f, 0.f};
    h = __builtin_amdgcn_mfma_f32_16x16x32_bf16(W1a[0], B0, h, 0, 0, 0);
    h = __builtin_amdgcn_mfma_f32_16x16x32_bf16(W1a[1], B1, h, 0, 0, 0);
    float hr[4];
    #pragma unroll
    for (int j = 0; j < 4; ++j) hr[j] = fmaxf(h[j] + gb1v[j], 0.f);

    float lg[6];
    #pragma unroll
    for (int kk = 0; kk < 6; ++kk) {
      const f32x4 w2 = *(const f32x4*)(gw2 + kk * 16 + kq * 4);
      lg[kk] = w2[0] * hr[0] + w2[1] * hr[1] + w2[2] * hr[2] + w2[3] * hr[3];
    }
    #pragma unroll
    for (int kk = 0; kk < 6; ++kk) lg[kk] += __shfl_xor(lg[kk], 16);
    #pragma unroll
    for (int kk = 0; kk < 6; ++kk) lg[kk] += __shfl_xor(lg[kk], 32);
    #pragma unroll
    for (int kk = 0; kk < 6; ++kk) lg[kk] += gb2[kk];

    float mx = fmaxf(fmaxf(fmaxf(lg[0], lg[1]), fmaxf(lg[2], lg[3])), fmaxf(lg[4], lg[5]));
    float ex[6], ssum = 0.f;
    #pragma unroll
    for (int kk = 0; kk < 6; ++kk) { ex[kk] = __expf(lg[kk] - mx); ssum += ex[kk]; }
    const float sinv = __builtin_amdgcn_rcpf(ssum);
    if (kq == 0) {
      f32x4 o0 = { ex[0] * sinv, ex[1] * sinv, ex[2] * sinv, ex[3] * sinv };
      f32x4 o1 = { ex[4] * sinv, ex[5] * sinv, 0.f, 0.f };
      *(f32x4*)&m.wmld[col * 8 + 0] = o0;
      *(f32x4*)&m.wmld[col * 8 + 4] = o1;
    }
  }
  __syncthreads();

  float* outb = outg + (size_t)b * (OCH * HW) + pbase;

  #pragma unroll
  for (int pg = 0; pg < 16; ++pg) {
    const int col = pg * 16 + lr;
    const bf16x8 B0 = *(const bf16x8*)&m.xt[col * 128 + ((kq       ^ (col & 7)) << 4)];
    const bf16x8 B1 = *(const bf16x8*)&m.xt[col * 128 + (((4 + kq) ^ (col & 7)) << 4)];
    const f32x4 wv0 = *(const f32x4*)&m.wmld[col * 8 + 0];
    const f32x4 wv1 = *(const f32x4*)&m.wmld[col * 8 + 4];
    const float wmv[6] = { wv0[0], wv0[1], wv0[2], wv0[3], wv1[0], wv1[1] };

    f32x4 facc = biasv;
    #pragma unroll
    for (int kk = 0; kk < 6; ++kk) {
      f32x4 y = {0.f, 0.f, 0.f, 0.f};
      y = __builtin_amdgcn_mfma_f32_16x16x32_bf16(A[2 * kk    ], B0, y, 0, 0, 0);
      y = __builtin_amdgcn_mfma_f32_16x16x32_bf16(A[2 * kk + 1], B1, y, 0, 0, 0);
      #pragma unroll
      for (int j = 0; j < 4; ++j) facc[j] += wmv[kk] * y[j];
    }
    #pragma unroll
    for (int j = 0; j < 4; ++j) {
      const int o = w * 16 + kq * 4 + j;
      __builtin_nontemporal_store(facc[j], &outb[(size_t)o * HW + col]);
    }
  }
}

extern "C" void kernel_launch(void* const* d_in, const int* in_sizes, int n_in,
                              void* d_out, int out_size, void* d_ws, size_t ws_size,
                              hipStream_t stream) {
  const float* x    = (const float*)d_in[0];
  const float* gw1  = (const float*)d_in[1];
  const float* gb1  = (const float*)d_in[2];
  const float* gw2  = (const float*)d_in[3];
  const float* gb2  = (const float*)d_in[4];
  const float* pw   = (const float*)d_in[5];
  const float* pb   = (const float*)d_in[6];
  const float* s53A = (const float*)d_in[7];
  const float* s53D = (const float*)d_in[8];
  const float* s97A = (const float*)d_in[9];
  const float* s97D = (const float*)d_in[10];
  __bf16* Pws = (__bf16*)d_ws;
  float* out = (float*)d_out;

  void* kargs[] = {
    (void*)&x, (void*)&gw1, (void*)&gb1, (void*)&gw2, (void*)&gb2,
    (void*)&pw, (void*)&pb, (void*)&s53A, (void*)&s53D, (void*)&s97A,
    (void*)&s97D, (void*)&Pws, (void*)&out
  };
  hipError_t err = hipLaunchCooperativeKernel(
      (const void*)fused, dim3(512), dim3(256), kargs, 0, stream);
  if (err != hipSuccess) {
    // fallback: proven two-kernel path (identical outputs)
    setup_P<<<384, 256, 0, stream>>>(pw, s53A, s53D, s97A, s97D, Pws);
    wavelet_main<<<512, 256, 0, stream>>>(x, gw1, gb1, gw2, gb2, pb, Pws, out);
  }
}

// Round 18
// 29.514 us; speedup vs baseline: 3.0610x; 3.0610x over previous
//
#include <hip/hip_runtime.h>
#include <hip/hip_bf16.h>
#include <math.h>

typedef __bf16 bf16x4 __attribute__((ext_vector_type(4)));
typedef __bf16 bf16x8 __attribute__((ext_vector_type(8)));
typedef float  f32x4  __attribute__((ext_vector_type(4)));

#define HW 16384   // 128*128
#define CCH 64
#define OCH 64

__device__ static const float FIRTAB[62] = {
  // db4 (8)
  -0.0105974017850021f, 0.0328830116668852f, 0.0308413818355607f, -0.1870348117188811f,
  -0.0279837694169839f, 0.6308807679295904f, 0.7148465705529155f, 0.2303778133088964f,
  // db6 (12)
  0.00107730108499558f, -0.00477725751101065f, -0.0005538422009938f, 0.03158203931748603f,
  0.02752286553030533f, -0.0975016055873225f, -0.12976686756709563f, 0.22626469396544f,
  0.3152503517092432f, -0.7511339080210959f, 0.4946238903984534f, 0.1115407433501095f,
  // sym6 (12)
  -0.007800708325034148f, 0.001767711864242804f, 0.04472490177066578f, -0.02106029251230056f,
  -0.0726375227866f, 0.3379294217282401f, 0.787641141030194f, 0.4910559419267466f,
  -0.048311742585632f, -0.1179901111484105f, 0.00349071208421747f, 0.01540410932702737f,
  // coif5 (30)
  -3.459977283621256e-05f, -7.098330313814114e-05f, 0.0004662169601128863f, 0.001117518770890601f,
  -0.002574517688750223f, -0.00900797613666158f, 0.015880544863615904f, 0.03455502757306163f,
  -0.08230192710688598f, -0.07179982161931202f, 0.42848347637761874f, 0.7937772226256206f,
  0.4051769024096169f, -0.06112339000267287f, -0.06577191128185562f, 0.023452696141836267f,
  0.007782596427325418f, -0.003793512864491014f, -0.0002606761356811993f, 0.000107502882505652f,
  1.10319778524429e-05f, -5.520763127949e-06f, -1.0682196848076e-06f, 5.236425333584e-07f,
  1.125098976034e-07f, -5.417490769329e-08f, -8.8631e-09f, 4.2921e-09f, 6.7e-10f, -3.2e-10f
};
__device__ static const int FIR_OFF[4] = {0, 8, 20, 32};
__device__ static const int FIR_LEN[4] = {8, 12, 12, 30};

// ---------------------------------------------------------------------------
// Kernel 1: data-parallel, latency-hole-free (proven: R14 bench, 29.71 total).
//  48 blocks (k = bid>>3, q = bid&7 folds rows q*8..q*8+7), 256 threads.
//  FIR: taps staged to LDS once; entry (i,c) via <=3 closed-form candidate
//  l values (l1=c+pl-i; l2=-c+pl-i if c>0; l3=126-c+pl-i if c<63).
//  Output layout (proven): entry (k,o,c) -> Pout[(((s*4+mf)*64+lane)<<3)+e],
//   s = 2k+(c>>5), mf = o>>4, lane = (o&15)|(((c&31)>>3)<<4), e = c&7
// ---------------------------------------------------------------------------
__global__ __launch_bounds__(256) void setup_P(
    const float* __restrict__ pw,
    const float* __restrict__ s53A, const float* __restrict__ s53D,
    const float* __restrict__ s97A, const float* __restrict__ s97D,
    __bf16* __restrict__ Pout)
{
  __shared__ float tmpA[62][64];
  __shared__ float tmpD[62][64];
  __shared__ float matA[64][64];
  __shared__ float matD[64][64];
  __shared__ float pwld[8][128];
  __shared__ float rawS[32], loS[32], hiS[32];

  const int k = blockIdx.x >> 3;
  const int q = blockIdx.x & 7;
  const int t = threadIdx.x;

  {
    const float* src = pw + q * 8 * 128;
    #pragma unroll
    for (int i = 0; i < 4; ++i)
      ((float*)pwld)[t + i * 256] = src[t + i * 256];
  }

  if (k < 4) {
    const int L = FIR_LEN[k], off = FIR_OFF[k];
    const int pl = (L - 1) / 2 - 1;          // even L for all four FIRs

    if (t < L) rawS[t] = FIRTAB[off + t];
    __syncthreads();
    float ss = 0.f;
    for (int l = 0; l < L; ++l) { float vv = rawS[l]; ss += vv * vv; }
    const float inv = 1.f / (sqrtf(ss) + 1e-12f);
    if (t < L) {
      loS[t] = rawS[t] * inv;
      hiS[t] = ((t & 1) ? -1.f : 1.f) * rawS[L - 1 - t] * inv;
    }
    __syncthreads();

    for (int e = t; e < 62 * 64; e += 256) {
      const int i = e >> 6, c = e & 63;
      const int base = pl - i;
      const int l1 = c + base;
      const int l2 = -c + base;
      const int l3 = 126 - c + base;
      float va = 0.f, vd = 0.f;
      if (l1 >= 0 && l1 < L)           { va += loS[l1]; vd += hiS[l1]; }
      if (c > 0 && l2 >= 0 && l2 < L)  { va += loS[l2]; vd += hiS[l2]; }
      if (c < 63 && l3 >= 0 && l3 < L) { va += loS[l3]; vd += hiS[l3]; }
      tmpA[i][c] = va; tmpD[i][c] = vd;
    }
    __syncthreads();
  } else {
    for (int e = t; e < 32 * 64; e += 256) {
      const int i = e >> 6, c = e & 63;
      tmpA[i][c] = (c == 2 * i)     ? 1.f : 0.f;
      tmpD[i][c] = (c == 2 * i + 1) ? 1.f : 0.f;
    }
    float cf[4]; int nst;
    if (k == 4) { cf[0] = -0.5f; cf[1] = 0.25f; cf[2] = 0.f; cf[3] = 0.f; nst = 2; }
    else { cf[0] = -1.586134342f; cf[1] = -0.05298011854f;
           cf[2] = 0.8829110762f; cf[3] = 0.4435068522f; nst = 4; }
    __syncthreads();
    for (int s = 0; s < nst; ++s) {
      for (int e = t; e < 32 * 64; e += 256) {
        const int i = e >> 6, c = e & 63;
        const int im = (i == 0) ? 1 : i - 1;
        const int ip = (i == 31) ? 30 : i + 1;
        if ((s & 1) == 0)
          tmpD[i][c] += cf[s] * 0.5f * (tmpA[im][c] + tmpA[ip][c]);
        else
          tmpA[i][c] += cf[s] * 0.5f * (tmpD[im][c] + tmpD[ip][c]);
      }
      __syncthreads();
    }
  }

  {
    const int Lin = (k < 4) ? 62 : 32;
    float sA = 1.f, sD = 1.f;
    if (k == 4) { sA = s53A[0]; sD = s53D[0]; }
    if (k == 5) { sA = s97A[0]; sD = s97D[0]; }
    const float step = (float)Lin / 64.0f;
    for (int e = t; e < 64 * 64; e += 256) {
      const int o = e >> 6, c = e & 63;
      float src = (o + 0.5f) * step - 0.5f;
      src = fmaxf(src, 0.f);
      int i0 = (int)floorf(src); if (i0 > Lin - 1) i0 = Lin - 1;
      int i1 = i0 + 1;           if (i1 > Lin - 1) i1 = Lin - 1;
      float w = src - (float)i0;
      matA[o][c] = sA * ((1.f - w) * tmpA[i0][c] + w * tmpA[i1][c]);
      matD[o][c] = sD * ((1.f - w) * tmpD[i0][c] + w * tmpD[i1][c]);
    }
  }
  __syncthreads();

  {
    const int oo = t >> 5;                   // 0..7
    const int o  = q * 8 + oo;
    const int c0 = (t & 31) * 2;
    float acc0 = 0.f, acc1 = 0.f;
    #pragma unroll 8
    for (int j = 0; j < 64; ++j) {
      const float wa = pwld[oo][j];
      const float wd = pwld[oo][64 + j];
      acc0 += wa * matA[j][c0]     + wd * matD[j][c0];
      acc1 += wa * matA[j][c0 + 1] + wd * matD[j][c0 + 1];
    }
    const int mf = o >> 4;
    #pragma unroll
    for (int cc = 0; cc < 2; ++cc) {
      const int c = c0 + cc;
      const int s = k * 2 + (c >> 5);
      const int lane = (o & 15) | (((c & 31) >> 3) << 4);
      const int e = c & 7;
      Pout[(((s * 4 + mf) * 64 + lane) << 3) + e] = (__bf16)(cc ? acc1 : acc0);
    }
  }
}

// ---------------------------------------------------------------------------
// Kernel 2 (proven best: measured 16.45 us warm via R12 differential).
// 1024 blocks x 256 threads; 128 px per block; single barrier.
// ---------------------------------------------------------------------------
__global__ __launch_bounds__(256, 2) void wavelet_main(
    const float* __restrict__ xg,
    const float* __restrict__ gw1, const float* __restrict__ gb1,
    const float* __restrict__ gw2, const float* __restrict__ gb2,
    const float* __restrict__ pbias,
    const __bf16* __restrict__ Pws,
    float* __restrict__ outg)
{
  __shared__ __align__(16) unsigned char xt[128 * 128];  // 16 KB
  __shared__ __align__(16) float wmld[128 * 8];          //  4 KB

  const int t    = threadIdx.x;
  const int w    = t >> 6;
  const int lane = t & 63;
  const int lr   = lane & 15;
  const int kq   = lane >> 4;

  const int blk   = blockIdx.x;
  const int b     = blk >> 7;                 // 128 tiles per image
  const int pbase = (blk & 127) << 7;         // 128 px per tile

  // ---- staging: own-wave px quad x all 64 channels ----
  const int pq  = lane & 7;                   // px quad within wave's 32
  const int cg  = lane >> 3;                  // 8-channel group 0..7
  const int px0 = w * 32 + pq * 4;

  const float* s = xg + (size_t)b * (CCH * HW) + (size_t)(cg * 8) * HW + pbase + px0;
  f32x4 v[8];
  #pragma unroll
  for (int r = 0; r < 8; ++r) v[r] = *(const f32x4*)(s + (size_t)r * HW);

  // ---- per-wave constants (latency hides under staging loads) ----
  bf16x8 A[12];
  #pragma unroll
  for (int kk = 0; kk < 6; ++kk)
    #pragma unroll
    for (int sh = 0; sh < 2; ++sh)
      A[kk * 2 + sh] = *(const bf16x8*)(Pws + (size_t)((((2 * kk + sh) * 4 + w) * 64 + lane) << 3));

  bf16x8 W1a[2];
  {
    const float* wp = gw1 + lr * 64 + kq * 8;
    #pragma unroll
    for (int hh = 0; hh < 2; ++hh) {
      f32x4 lo = *(const f32x4*)(wp + hh * 32);
      f32x4 hi = *(const f32x4*)(wp + hh * 32 + 4);
      bf16x8 a;
      #pragma unroll
      for (int e = 0; e < 4; ++e) { a[e] = (__bf16)lo[e]; a[e + 4] = (__bf16)hi[e]; }
      W1a[hh] = a;
    }
  }
  const f32x4 gb1v  = *(const f32x4*)(gb1 + kq * 4);
  const f32x4 biasv = *(const f32x4*)(pbias + w * 16 + kq * 4);

  // ---- write own 8ch x 4px into swizzled bf16 tile ----
  #pragma unroll
  for (int i = 0; i < 4; ++i) {
    const int px = px0 + i;
    bf16x8 wv;
    #pragma unroll
    for (int e = 0; e < 8; ++e) wv[e] = (__bf16)v[e][i];
    *(bf16x8*)&xt[px * 128 + ((cg ^ (px & 7)) << 4)] = wv;
  }

  // ---- phase A (pre-barrier): gate the wave's OWN two pixel-groups ----
  #pragma unroll
  for (int pp = 0; pp < 2; ++pp) {
    const int col = (2 * w + pp) * 16 + lr;   // in [w*32, w*32+32): own-staged
    const bf16x8 B0 = *(const bf16x8*)&xt[col * 128 + ((kq       ^ (col & 7)) << 4)];
    const bf16x8 B1 = *(const bf16x8*)&xt[col * 128 + (((4 + kq) ^ (col & 7)) << 4)];

    f32x4 h = {0.f, 0.f, 0.f, 0.f};
    h = __builtin_amdgcn_mfma_f32_16x16x32_bf16(W1a[0], B0, h, 0, 0, 0);
    h = __builtin_amdgcn_mfma_f32_16x16x32_bf16(W1a[1], B1, h, 0, 0, 0);
    float hr[4];
    #pragma unroll
    for (int j = 0; j < 4; ++j) hr[j] = fmaxf(h[j] + gb1v[j], 0.f);

    float lg[6];
    #pragma unroll
    for (int kk = 0; kk < 6; ++kk) {
      const f32x4 w2 = *(const f32x4*)(gw2 + kk * 16 + kq * 4);
      lg[kk] = w2[0] * hr[0] + w2[1] * hr[1] + w2[2] * hr[2] + w2[3] * hr[3];
    }
    #pragma unroll
    for (int kk = 0; kk < 6; ++kk) lg[kk] += __shfl_xor(lg[kk], 16);
    #pragma unroll
    for (int kk = 0; kk < 6; ++kk) lg[kk] += __shfl_xor(lg[kk], 32);
    #pragma unroll
    for (int kk = 0; kk < 6; ++kk) lg[kk] += gb2[kk];

    float mx = fmaxf(fmaxf(fmaxf(lg[0], lg[1]), fmaxf(lg[2], lg[3])), fmaxf(lg[4], lg[5]));
    float ex[6], ssum = 0.f;
    #pragma unroll
    for (int kk = 0; kk < 6; ++kk) { ex[kk] = __expf(lg[kk] - mx); ssum += ex[kk]; }
    const float sinv = __builtin_amdgcn_rcpf(ssum);
    // softmax sums to 1 (+-3e-7): reference's renorm /(sum+1e-12) is a no-op
    if (kq == 0) {
      f32x4 o0 = { ex[0] * sinv, ex[1] * sinv, ex[2] * sinv, ex[3] * sinv };
      f32x4 o1 = { ex[4] * sinv, ex[5] * sinv, 0.f, 0.f };
      *(f32x4*)&wmld[col * 8 + 0] = o0;
      *(f32x4*)&wmld[col * 8 + 4] = o1;
    }
  }
  __syncthreads();   // the ONLY barrier

  // ---- phase B: main MFMA over all 8 pixel-groups, scattered stores ----
  float* outb = outg + (size_t)b * (OCH * HW) + pbase;

  #pragma unroll
  for (int pg = 0; pg < 8; ++pg) {
    const int col = pg * 16 + lr;
    const bf16x8 B0 = *(const bf16x8*)&xt[col * 128 + ((kq       ^ (col & 7)) << 4)];
    const bf16x8 B1 = *(const bf16x8*)&xt[col * 128 + (((4 + kq) ^ (col & 7)) << 4)];
    const f32x4 wv0 = *(const f32x4*)&wmld[col * 8 + 0];
    const f32x4 wv1 = *(const f32x4*)&wmld[col * 8 + 4];
    const float wmv[6] = { wv0[0], wv0[1], wv0[2], wv0[3], wv1[0], wv1[1] };

    f32x4 facc = biasv;
    #pragma unroll
    for (int kk = 0; kk < 6; ++kk) {
      f32x4 y = {0.f, 0.f, 0.f, 0.f};
      y = __builtin_amdgcn_mfma_f32_16x16x32_bf16(A[2 * kk    ], B0, y, 0, 0, 0);
      y = __builtin_amdgcn_mfma_f32_16x16x32_bf16(A[2 * kk + 1], B1, y, 0, 0, 0);
      #pragma unroll
      for (int j = 0; j < 4; ++j) facc[j] += wmv[kk] * y[j];
    }
    #pragma unroll
    for (int j = 0; j < 4; ++j) {
      const int o = w * 16 + kq * 4 + j;
      outb[(size_t)o * HW + col] = facc[j];
    }
  }
}

extern "C" void kernel_launch(void* const* d_in, const int* in_sizes, int n_in,
                              void* d_out, int out_size, void* d_ws, size_t ws_size,
                              hipStream_t stream) {
  const float* x    = (const float*)d_in[0];
  const float* gw1  = (const float*)d_in[1];
  const float* gb1  = (const float*)d_in[2];
  const float* gw2  = (const float*)d_in[3];
  const float* gb2  = (const float*)d_in[4];
  const float* pw   = (const float*)d_in[5];
  const float* pb   = (const float*)d_in[6];
  const float* s53A = (const float*)d_in[7];
  const float* s53D = (const float*)d_in[8];
  const float* s97A = (const float*)d_in[9];
  const float* s97D = (const float*)d_in[10];
  __bf16* Pws = (__bf16*)d_ws;
  float* out = (float*)d_out;

  setup_P<<<48, 256, 0, stream>>>(pw, s53A, s53D, s97A, s97D, Pws);
  wavelet_main<<<1024, 256, 0, stream>>>(x, gw1, gb1, gw2, gb2, pb, Pws, out);
}